// Round 1
// baseline (964.285 us; speedup 1.0000x reference)
//
#include <hip/hip_runtime.h>
#include <math.h>

#define NN 20000
#define NE 320000
#define NTOT (NE + NN)
#define NBATCH 64
#define HIDW 256
#define NHEADS 8
#define HD 32
#define NL 4
#define BEPS 1e-5f
#define LSLOPE 0.2f

// ---------------- CSR build ----------------
__global__ void k_hist(const int* __restrict__ dst, int* __restrict__ cnt) {
  int i = blockIdx.x * blockDim.x + threadIdx.x;
  if (i >= NTOT) return;
  int d = (i < NE) ? dst[i] : (i - NE);
  atomicAdd(&cnt[d], 1);
}

__global__ __launch_bounds__(1024) void k_scan(const int* __restrict__ cnt,
                                               int* __restrict__ rowptr) {
  __shared__ int tsum[1024];
  int tid = threadIdx.x;
  const int per = (NN + 1023) / 1024;  // 20
  int start = tid * per;
  int local = 0;
  for (int j = 0; j < per; ++j) {
    int idx = start + j;
    if (idx < NN) local += cnt[idx];
  }
  tsum[tid] = local;
  __syncthreads();
  for (int off = 1; off < 1024; off <<= 1) {
    int v = (tid >= off) ? tsum[tid - off] : 0;
    __syncthreads();
    tsum[tid] += v;
    __syncthreads();
  }
  int run = (tid == 0) ? 0 : tsum[tid - 1];
  for (int j = 0; j < per; ++j) {
    int idx = start + j;
    if (idx < NN) { rowptr[idx] = run; run += cnt[idx]; }
  }
  if (tid == 1023) rowptr[NN] = tsum[1023];
}

__global__ void k_fill(const int* __restrict__ src, const int* __restrict__ dst,
                       const int* __restrict__ rowptr, int* __restrict__ cur,
                       int* __restrict__ srcs, int* __restrict__ eids) {
  int i = blockIdx.x * blockDim.x + threadIdx.x;
  if (i >= NTOT) return;
  int s = (i < NE) ? src[i] : (i - NE);
  int d = (i < NE) ? dst[i] : (i - NE);
  int pos = rowptr[d] + atomicAdd(&cur[d], 1);
  srcs[pos] = s;
  eids[pos] = i;
}

// ---------------- fp32 tiled GEMM: C[M,Nc] = act(A[M,K] @ W[K,Nc] (+bias)) ----------------
#define BM 64
#define BN 64
#define BKK 32
__global__ __launch_bounds__(256) void k_gemm(const float* __restrict__ A,
                                              const float* __restrict__ W,
                                              const float* __restrict__ bias,
                                              float* __restrict__ C,
                                              int M, int K, int Nc, int relu) {
  __shared__ float As[BKK][BM + 4];  // stride 68 floats = 272B (16B aligned)
  __shared__ float Ws[BKK][BN + 4];
  int tid = threadIdx.x;
  int row0 = blockIdx.x * BM, col0 = blockIdx.y * BN;
  int tx = tid & 15, ty = tid >> 4;
  float acc[4][4] = {};
  for (int k0 = 0; k0 < K; k0 += BKK) {
#pragma unroll
    for (int L = 0; L < 2; ++L) {
      int idx = tid + L * 256;
      int m = idx >> 3, kq = idx & 7;
      int r = row0 + m;
      float4 v = make_float4(0.f, 0.f, 0.f, 0.f);
      if (r < M) v = *reinterpret_cast<const float4*>(&A[(size_t)r * K + k0 + kq * 4]);
      As[kq * 4 + 0][m] = v.x;
      As[kq * 4 + 1][m] = v.y;
      As[kq * 4 + 2][m] = v.z;
      As[kq * 4 + 3][m] = v.w;
    }
#pragma unroll
    for (int L = 0; L < 2; ++L) {
      int idx = tid + L * 256;
      int kk = idx >> 4, nq = idx & 15;
      float4 v = *reinterpret_cast<const float4*>(&W[(size_t)(k0 + kk) * Nc + col0 + nq * 4]);
      *reinterpret_cast<float4*>(&Ws[kk][nq * 4]) = v;
    }
    __syncthreads();
#pragma unroll
    for (int k = 0; k < BKK; ++k) {
      float4 a = *reinterpret_cast<const float4*>(&As[k][ty * 4]);
      float4 b = *reinterpret_cast<const float4*>(&Ws[k][tx * 4]);
      float av[4] = {a.x, a.y, a.z, a.w};
      float bv[4] = {b.x, b.y, b.z, b.w};
#pragma unroll
      for (int i = 0; i < 4; ++i)
#pragma unroll
        for (int j = 0; j < 4; ++j) acc[i][j] += av[i] * bv[j];
    }
    __syncthreads();
  }
#pragma unroll
  for (int i = 0; i < 4; ++i) {
    int r = row0 + ty * 4 + i;
    if (r >= M) continue;
#pragma unroll
    for (int j = 0; j < 4; ++j) {
      int c = col0 + tx * 4 + j;
      float v = acc[i][j];
      if (bias) v += bias[c];
      if (relu) v = fmaxf(v, 0.f);
      C[(size_t)r * Nc + c] = v;
    }
  }
}

// ---------------- GAT pieces ----------------
__global__ void k_gat_att(const float* __restrict__ h, const float* __restrict__ a_src,
                          const float* __restrict__ a_dst, float* __restrict__ asrc,
                          float* __restrict__ adst) {
  int i = blockIdx.x * blockDim.x + threadIdx.x;  // (node, head)
  if (i >= NN * NHEADS) return;
  int node = i >> 3, hh = i & 7;
  const float* hp = &h[(size_t)node * HIDW + hh * HD];
  float s1 = 0.f, s2 = 0.f;
#pragma unroll
  for (int d = 0; d < HD; ++d) {
    float v = hp[d];
    s1 += v * a_src[hh * HD + d];
    s2 += v * a_dst[hh * HD + d];
  }
  asrc[i] = s1;
  adst[i] = s2;
}

__global__ void k_gat_edge(const int* __restrict__ src, const int* __restrict__ dst,
                           const float* __restrict__ asrc, const float* __restrict__ adst,
                           float* __restrict__ ex, float* __restrict__ ssum) {
  int i = blockIdx.x * blockDim.x + threadIdx.x;  // (edge, head)
  if (i >= NTOT * NHEADS) return;
  int e = i >> 3, hh = i & 7;
  int s = (e < NE) ? src[e] : (e - NE);
  int d = (e < NE) ? dst[e] : (e - NE);
  float v = asrc[s * NHEADS + hh] + adst[d * NHEADS + hh];
  v = (v >= 0.f) ? v : LSLOPE * v;
  float eexp = expf(v);  // max-subtraction removable: logits are O(1)
  ex[i] = eexp;
  atomicAdd(&ssum[d * NHEADS + hh], eexp);
}

// one wave per node; lane covers 4 channels (float4)
__global__ __launch_bounds__(256) void k_gat_agg(const float* __restrict__ h,
                                                 const int* __restrict__ rowptr,
                                                 const int* __restrict__ srcs,
                                                 const int* __restrict__ eids,
                                                 const float* __restrict__ ex,
                                                 const float* __restrict__ ssum,
                                                 float* __restrict__ out) {
  int wave = (blockIdx.x * blockDim.x + threadIdx.x) >> 6;
  int lane = threadIdx.x & 63;
  if (wave >= NN) return;
  int hh = lane >> 3;  // (lane*4)/32
  int beg = rowptr[wave], end = rowptr[wave + 1];
  float4 acc = make_float4(0.f, 0.f, 0.f, 0.f);
  for (int p = beg; p < end; ++p) {
    int s = srcs[p];
    float a = ex[(size_t)eids[p] * NHEADS + hh];
    float4 v = *reinterpret_cast<const float4*>(&h[(size_t)s * HIDW + lane * 4]);
    acc.x += a * v.x;
    acc.y += a * v.y;
    acc.z += a * v.z;
    acc.w += a * v.w;
  }
  float inv = 1.f / ssum[wave * NHEADS + hh];
  acc.x *= inv; acc.y *= inv; acc.z *= inv; acc.w *= inv;
  *reinterpret_cast<float4*>(&out[(size_t)wave * HIDW + lane * 4]) = acc;
}

// ---------------- BatchNorm (training-mode batch stats) + ReLU ----------------
__global__ void k_bn_stats(const float* __restrict__ x, float* __restrict__ stats) {
  int c = threadIdx.x;  // 256 channels
  float s = 0.f, s2 = 0.f;
  for (int r = blockIdx.x; r < NN; r += gridDim.x) {
    float v = x[(size_t)r * HIDW + c];
    s += v;
    s2 += v * v;
  }
  atomicAdd(&stats[c], s);
  atomicAdd(&stats[HIDW + c], s2);
}

__global__ void k_bn_fin(const float* __restrict__ stats, float* __restrict__ mr) {
  int c = threadIdx.x;
  float mean = stats[c] * (1.f / NN);
  float var = stats[HIDW + c] * (1.f / NN) - mean * mean;
  var = fmaxf(var, 0.f);
  mr[c] = mean;
  mr[HIDW + c] = rsqrtf(var + BEPS);
}

__global__ void k_bn_apply(float* __restrict__ x, const float* __restrict__ mr,
                           const float* __restrict__ g, const float* __restrict__ b) {
  int i = blockIdx.x * blockDim.x + threadIdx.x;
  if (i >= NN * HIDW) return;
  int c = i & 255;
  float v = x[i];
  v = g[c] * (v - mr[c]) * mr[HIDW + c] + b[c];
  x[i] = fmaxf(v, 0.f);
}

// ---------------- mean pool ----------------
__global__ void k_pool_acc(const float* __restrict__ x, const int* __restrict__ batch,
                           float* __restrict__ pool, int* __restrict__ cnt) {
  int i = blockIdx.x * blockDim.x + threadIdx.x;
  if (i >= NN * HIDW) return;
  int r = i >> 8, c = i & 255;
  int b = batch[r];
  atomicAdd(&pool[b * HIDW + c], x[i]);
  if (c == 0) atomicAdd(&cnt[b], 1);
}

__global__ void k_pool_div(float* __restrict__ pool, const int* __restrict__ cnt) {
  int i = blockIdx.x * blockDim.x + threadIdx.x;  // 64*256
  int b = i >> 8;
  pool[i] /= fmaxf((float)cnt[b], 1.f);
}

// ---------------- tiny head (B=64) ----------------
__global__ void k_head_mm(const float* __restrict__ x, const float* __restrict__ W,
                          const float* __restrict__ bias, float* __restrict__ y,
                          int K, int No, int relu) {
  __shared__ float xr[512];
  int bb = blockIdx.x, c = threadIdx.x;
  for (int k = c; k < K; k += blockDim.x) xr[k] = x[bb * K + k];
  __syncthreads();
  if (c >= No) return;
  float acc = bias ? bias[c] : 0.f;
  for (int k = 0; k < K; ++k) acc += xr[k] * W[k * No + c];
  if (relu) acc = fmaxf(acc, 0.f);
  y[bb * No + c] = acc;
}

__global__ void k_head_fus(const float* __restrict__ x1, const float* __restrict__ x2,
                           const float* __restrict__ W, const float* __restrict__ bias,
                           float* __restrict__ y) {
  __shared__ float xr[512];
  int bb = blockIdx.x, c = threadIdx.x;  // 256
  xr[c] = x1[bb * HIDW + c];
  xr[HIDW + c] = x2[bb * HIDW + c];
  __syncthreads();
  float acc = bias[c];
  for (int k = 0; k < 512; ++k) acc += xr[k] * W[k * HIDW + c];
  y[bb * HIDW + c] = fmaxf(acc, 0.f);
}

__global__ void k_head_out(const float* __restrict__ h1, const float* __restrict__ W,
                           const float* __restrict__ b, float* __restrict__ out) {
  __shared__ float red[128];
  int bb = blockIdx.x, t = threadIdx.x;  // 128
  red[t] = h1[bb * 128 + t] * W[t];
  __syncthreads();
  for (int off = 64; off; off >>= 1) {
    if (t < off) red[t] += red[t + off];
    __syncthreads();
  }
  if (t == 0) out[bb] = red[0] + b[0];
}

// ---------------- launch ----------------
extern "C" void kernel_launch(void* const* d_in, const int* in_sizes, int n_in,
                              void* d_out, int out_size, void* d_ws, size_t ws_size,
                              hipStream_t stream) {
  // NOTE: seq branch (d_in[0],2,4,6..11) and Wq/bq/Wk/bk (20..23) are dead code:
  // softmax over the singleton score axis is identically 1, so x_attn depends only on xt.
  const float* struct_x = (const float*)d_in[1];
  const int* edge = (const int*)d_in[3];  // [2,E]: row0=src, row1=dst
  const int* batch = (const int*)d_in[5];
  const float* projW = (const float*)d_in[12];
  const float* projB = (const float*)d_in[13];
  const float* gatW = (const float*)d_in[14];
  const float* attS = (const float*)d_in[15];
  const float* attD = (const float*)d_in[16];
  // gat_b (17) cancels inside BatchNorm
  const float* bnG = (const float*)d_in[18];
  const float* bnB = (const float*)d_in[19];
  const float* Wv = (const float*)d_in[24];
  const float* bv = (const float*)d_in[25];
  const float* Wo = (const float*)d_in[26];
  const float* bo = (const float*)d_in[27];
  const float* fusW = (const float*)d_in[28];
  const float* fusB = (const float*)d_in[29];
  const float* p1W = (const float*)d_in[30];
  const float* p1b = (const float*)d_in[31];
  const float* p2W = (const float*)d_in[32];
  const float* p2b = (const float*)d_in[33];
  float* out = (float*)d_out;

  const int* e_src = edge;
  const int* e_dst = edge + NE;

  char* ws = (char*)d_ws;
  size_t off = 0;
  auto alloc = [&](size_t bytes) -> void* {
    void* p = ws + off;
    off = (off + bytes + 255) & ~(size_t)255;
    return p;
  };
  float* buf0 = (float*)alloc((size_t)NN * HIDW * 4);
  float* buf1 = (float*)alloc((size_t)NN * HIDW * 4);
  int* rowptr = (int*)alloc((NN + 1) * 4);
  int* cur = (int*)alloc(NN * 4);
  int* srcs = (int*)alloc((size_t)NTOT * 4);
  int* eids = (int*)alloc((size_t)NTOT * 4);
  float* asrc = (float*)alloc((size_t)NN * NHEADS * 4);
  float* adst = (float*)alloc((size_t)NN * NHEADS * 4);
  float* ssum = (float*)alloc((size_t)NN * NHEADS * 4);
  float* exb = (float*)alloc((size_t)NTOT * NHEADS * 4);
  float* stats = (float*)alloc(512 * 4);
  float* mr = (float*)alloc(512 * 4);
  float* pool = (float*)alloc(NBATCH * HIDW * 4);
  int* pcnt = (int*)alloc(NBATCH * 4);
  float* hv = (float*)alloc(NBATCH * HIDW * 4);
  float* hx = (float*)alloc(NBATCH * HIDW * 4);
  float* hf = (float*)alloc(NBATCH * HIDW * 4);
  float* h1 = (float*)alloc(NBATCH * 128 * 4);

  const int TPB = 256;
  const int gEdge = (NTOT + TPB - 1) / TPB;

  // ---- CSR for struct graph (with self loops appended) ----
  hipMemsetAsync(cur, 0, NN * 4, stream);
  k_hist<<<gEdge, TPB, 0, stream>>>(e_dst, cur);
  k_scan<<<1, 1024, 0, stream>>>(cur, rowptr);
  hipMemsetAsync(cur, 0, NN * 4, stream);
  k_fill<<<gEdge, TPB, 0, stream>>>(e_src, e_dst, rowptr, cur, srcs, eids);

  // ---- struct projection: buf0 = relu(struct_x @ projW + projB) ----
  dim3 gemmGrid((NN + BM - 1) / BM, HIDW / BN);
  k_gemm<<<gemmGrid, 256, 0, stream>>>(struct_x, projW, projB, buf0, NN, 128, HIDW, 1);

  // ---- 4 GAT layers ----
  for (int l = 0; l < NL; ++l) {
    // h = buf0 @ gat_W[l]  (bias cancels in BN)
    k_gemm<<<gemmGrid, 256, 0, stream>>>(buf0, gatW + (size_t)l * HIDW * HIDW, nullptr,
                                         buf1, NN, HIDW, HIDW, 0);
    k_gat_att<<<(NN * NHEADS + TPB - 1) / TPB, TPB, 0, stream>>>(
        buf1, attS + l * HIDW, attD + l * HIDW, asrc, adst);
    hipMemsetAsync(ssum, 0, (size_t)NN * NHEADS * 4, stream);
    k_gat_edge<<<(NTOT * NHEADS + TPB - 1) / TPB, TPB, 0, stream>>>(e_src, e_dst, asrc,
                                                                    adst, exb, ssum);
    k_gat_agg<<<(NN * 64 + TPB - 1) / TPB, TPB, 0, stream>>>(buf1, rowptr, srcs, eids,
                                                             exb, ssum, buf0);
    hipMemsetAsync(stats, 0, 512 * 4, stream);
    k_bn_stats<<<256, 256, 0, stream>>>(buf0, stats);
    k_bn_fin<<<1, 256, 0, stream>>>(stats, mr);
    k_bn_apply<<<(NN * HIDW) / TPB, TPB, 0, stream>>>(buf0, mr, bnG + l * HIDW,
                                                      bnB + l * HIDW);
  }

  // ---- mean pool over batch ----
  hipMemsetAsync(pool, 0, NBATCH * HIDW * 4, stream);
  hipMemsetAsync(pcnt, 0, NBATCH * 4, stream);
  k_pool_acc<<<(NN * HIDW) / TPB, TPB, 0, stream>>>(buf0, batch, pool, pcnt);
  k_pool_div<<<NBATCH, 256, 0, stream>>>(pool, pcnt);

  // ---- head: x_attn = (pool@Wv+bv)@Wo+bo ; fus ; p1 ; p2 ----
  k_head_mm<<<NBATCH, 256, 0, stream>>>(pool, Wv, bv, hv, HIDW, HIDW, 0);
  k_head_mm<<<NBATCH, 256, 0, stream>>>(hv, Wo, bo, hx, HIDW, HIDW, 0);
  k_head_fus<<<NBATCH, 256, 0, stream>>>(hx, pool, fusW, fusB, hf);
  k_head_mm<<<NBATCH, 128, 0, stream>>>(hf, p1W, p1b, h1, HIDW, 128, 1);
  k_head_out<<<NBATCH, 128, 0, stream>>>(h1, p2W, p2b, out);
}

// Round 2
// 718.314 us; speedup vs baseline: 1.3424x; 1.3424x over previous
//
#include <hip/hip_runtime.h>
#include <math.h>

#define NN 20000
#define NE 320000
#define NTOT (NE + NN)
#define NBATCH 64
#define HIDW 256
#define NHEADS 8
#define HD 32
#define NL 4
#define BEPS 1e-5f
#define LSLOPE 0.2f

// ---------------- CSR build ----------------
__global__ void k_hist(const int* __restrict__ dst, int* __restrict__ cnt) {
  int i = blockIdx.x * blockDim.x + threadIdx.x;
  if (i >= NTOT) return;
  int d = (i < NE) ? dst[i] : (i - NE);
  atomicAdd(&cnt[d], 1);
}

__global__ __launch_bounds__(1024) void k_scan(const int* __restrict__ cnt,
                                               int* __restrict__ rowptr) {
  __shared__ int tsum[1024];
  int tid = threadIdx.x;
  const int per = (NN + 1023) / 1024;  // 20
  int start = tid * per;
  int local = 0;
  for (int j = 0; j < per; ++j) {
    int idx = start + j;
    if (idx < NN) local += cnt[idx];
  }
  tsum[tid] = local;
  __syncthreads();
  for (int off = 1; off < 1024; off <<= 1) {
    int v = (tid >= off) ? tsum[tid - off] : 0;
    __syncthreads();
    tsum[tid] += v;
    __syncthreads();
  }
  int run = (tid == 0) ? 0 : tsum[tid - 1];
  for (int j = 0; j < per; ++j) {
    int idx = start + j;
    if (idx < NN) { rowptr[idx] = run; run += cnt[idx]; }
  }
  if (tid == 1023) rowptr[NN] = tsum[1023];
}

__global__ void k_fill(const int* __restrict__ src, const int* __restrict__ dst,
                       const int* __restrict__ rowptr, int* __restrict__ cur,
                       int* __restrict__ srcs) {
  int i = blockIdx.x * blockDim.x + threadIdx.x;
  if (i >= NTOT) return;
  int s = (i < NE) ? src[i] : (i - NE);
  int d = (i < NE) ? dst[i] : (i - NE);
  int pos = rowptr[d] + atomicAdd(&cur[d], 1);
  srcs[pos] = s;
}

// ---------------- fp32 tiled GEMM, 128x128 tile, 8x8 per thread ----------------
// mode 0 (proj): C = relu(A@W + bias)
// mode 1 (gat):  C = A@W raw; also asrc/adst = (C reshaped heads)·aS/aD
// scsh != null: A element (row r, channel k) -> relu(v*scsh[k] + scsh[256+k]) on load
#define BM 128
#define BN 128
#define BKK 16
__global__ __launch_bounds__(256) void k_gemm(const float* __restrict__ A,
                                              const float* __restrict__ W,
                                              const float* __restrict__ bias,
                                              const float* __restrict__ scsh,
                                              const float* __restrict__ aS,
                                              const float* __restrict__ aD,
                                              float* __restrict__ C,
                                              float* __restrict__ asrc,
                                              float* __restrict__ adst,
                                              int M, int K, int Nc, int mode) {
  __shared__ float As[BKK][BM + 4];
  __shared__ float Ws[BKK][BN + 4];
  int tid = threadIdx.x;
  int row0 = blockIdx.x * BM, col0 = blockIdx.y * BN;
  int tx = tid & 15, ty = tid >> 4;
  float acc[8][8] = {};
  for (int k0 = 0; k0 < K; k0 += BKK) {
#pragma unroll
    for (int L = 0; L < 2; ++L) {
      int idx = tid + L * 256;
      int m = idx >> 2, kq = idx & 3;
      int r = row0 + m;
      float4 v = make_float4(0.f, 0.f, 0.f, 0.f);
      if (r < M) v = *reinterpret_cast<const float4*>(&A[(size_t)r * K + k0 + kq * 4]);
      if (scsh) {
        int kc = k0 + kq * 4;
        v.x = fmaxf(v.x * scsh[kc + 0] + scsh[HIDW + kc + 0], 0.f);
        v.y = fmaxf(v.y * scsh[kc + 1] + scsh[HIDW + kc + 1], 0.f);
        v.z = fmaxf(v.z * scsh[kc + 2] + scsh[HIDW + kc + 2], 0.f);
        v.w = fmaxf(v.w * scsh[kc + 3] + scsh[HIDW + kc + 3], 0.f);
      }
      As[kq * 4 + 0][m] = v.x;
      As[kq * 4 + 1][m] = v.y;
      As[kq * 4 + 2][m] = v.z;
      As[kq * 4 + 3][m] = v.w;
    }
#pragma unroll
    for (int L = 0; L < 2; ++L) {
      int idx = tid + L * 256;
      int kk = idx >> 5, nq = idx & 31;
      float4 v = *reinterpret_cast<const float4*>(&W[(size_t)(k0 + kk) * Nc + col0 + nq * 4]);
      *reinterpret_cast<float4*>(&Ws[kk][nq * 4]) = v;
    }
    __syncthreads();
#pragma unroll
    for (int k = 0; k < BKK; ++k) {
      float4 a0 = *reinterpret_cast<const float4*>(&As[k][ty * 8]);
      float4 a1 = *reinterpret_cast<const float4*>(&As[k][ty * 8 + 4]);
      float4 b0 = *reinterpret_cast<const float4*>(&Ws[k][tx * 8]);
      float4 b1 = *reinterpret_cast<const float4*>(&Ws[k][tx * 8 + 4]);
      float av[8] = {a0.x, a0.y, a0.z, a0.w, a1.x, a1.y, a1.z, a1.w};
      float bv[8] = {b0.x, b0.y, b0.z, b0.w, b1.x, b1.y, b1.z, b1.w};
#pragma unroll
      for (int i = 0; i < 8; ++i)
#pragma unroll
        for (int j = 0; j < 8; ++j) acc[i][j] += av[i] * bv[j];
    }
    __syncthreads();
  }

  if (mode == 0) {
    float bb[8];
#pragma unroll
    for (int j = 0; j < 8; ++j) bb[j] = bias[col0 + tx * 8 + j];
#pragma unroll
    for (int i = 0; i < 8; ++i) {
      int r = row0 + ty * 8 + i;
      if (r >= M) continue;
#pragma unroll
      for (int j = 0; j < 8; ++j) {
        C[(size_t)r * Nc + col0 + tx * 8 + j] = fmaxf(acc[i][j] + bb[j], 0.f);
      }
    }
  } else {
    // raw store of h
#pragma unroll
    for (int i = 0; i < 8; ++i) {
      int r = row0 + ty * 8 + i;
      if (r >= M) continue;
      float4 o0 = make_float4(acc[i][0], acc[i][1], acc[i][2], acc[i][3]);
      float4 o1 = make_float4(acc[i][4], acc[i][5], acc[i][6], acc[i][7]);
      *reinterpret_cast<float4*>(&C[(size_t)r * Nc + col0 + tx * 8]) = o0;
      *reinterpret_cast<float4*>(&C[(size_t)r * Nc + col0 + tx * 8 + 4]) = o1;
    }
    // attention logits: this block fully owns heads by*4 .. by*4+3
    int hg = blockIdx.y * 4 + (tx >> 2);          // global head
    int cih0 = (tx & 3) * 8;                      // col-in-head base
    float asv[8], adv[8];
#pragma unroll
    for (int j = 0; j < 8; ++j) {
      asv[j] = aS[hg * HD + cih0 + j];
      adv[j] = aD[hg * HD + cih0 + j];
    }
#pragma unroll
    for (int i = 0; i < 8; ++i) {
      float pa = 0.f, pd = 0.f;
#pragma unroll
      for (int j = 0; j < 8; ++j) {
        pa += acc[i][j] * asv[j];
        pd += acc[i][j] * adv[j];
      }
      pa += __shfl_xor(pa, 1); pa += __shfl_xor(pa, 2);
      pd += __shfl_xor(pd, 1); pd += __shfl_xor(pd, 2);
      int r = row0 + ty * 8 + i;
      if ((tx & 3) == 0 && r < M) {
        asrc[r * NHEADS + hg] = pa;
        adst[r * NHEADS + hg] = pd;
      }
    }
  }
}

// ---------------- fused GAT aggregation: edge softmax + gather in one pass ----------------
// one wave per node; lane covers 4 channels; head hh = lane>>3 recomputes its own ex
__global__ __launch_bounds__(256) void k_agg(const float* __restrict__ h,
                                             const int* __restrict__ rowptr,
                                             const int* __restrict__ srcs,
                                             const float* __restrict__ asrc,
                                             const float* __restrict__ adst,
                                             float* __restrict__ out) {
  int wid = (blockIdx.x * blockDim.x + threadIdx.x) >> 6;
  int lane = threadIdx.x & 63;
  if (wid >= NN) return;
  int hh = lane >> 3;
  float adn = adst[wid * NHEADS + hh];
  int beg = rowptr[wid], end = rowptr[wid + 1];
  float4 acc = make_float4(0.f, 0.f, 0.f, 0.f);
  float ssum = 0.f;
  for (int p = beg; p < end; ++p) {
    int s = srcs[p];
    float e = asrc[s * NHEADS + hh] + adn;
    e = (e >= 0.f) ? e : LSLOPE * e;
    float ex = __expf(e);  // max-subtraction removable: logits are O(1)
    ssum += ex;
    float4 v = *reinterpret_cast<const float4*>(&h[(size_t)s * HIDW + lane * 4]);
    acc.x += ex * v.x;
    acc.y += ex * v.y;
    acc.z += ex * v.z;
    acc.w += ex * v.w;
  }
  float inv = 1.f / ssum;
  acc.x *= inv; acc.y *= inv; acc.z *= inv; acc.w *= inv;
  *reinterpret_cast<float4*>(&out[(size_t)wid * HIDW + lane * 4]) = acc;
}

// ---------------- BatchNorm stats -> (scale, shift) ----------------
__global__ void k_bn_stats(const float* __restrict__ x, float* __restrict__ stats) {
  int c = threadIdx.x;  // 256 channels
  float s = 0.f, s2 = 0.f;
  for (int r = blockIdx.x; r < NN; r += gridDim.x) {
    float v = x[(size_t)r * HIDW + c];
    s += v;
    s2 += v * v;
  }
  atomicAdd(&stats[c], s);
  atomicAdd(&stats[HIDW + c], s2);
}

__global__ void k_bn_fin(const float* __restrict__ stats, const float* __restrict__ g,
                         const float* __restrict__ b, float* __restrict__ scsh) {
  int c = threadIdx.x;
  float mean = stats[c] * (1.f / NN);
  float var = stats[HIDW + c] * (1.f / NN) - mean * mean;
  var = fmaxf(var, 0.f);
  float sc = g[c] * rsqrtf(var + BEPS);
  scsh[c] = sc;
  scsh[HIDW + c] = b[c] - mean * sc;
}

// ---------------- mean pool (sorted batch, segmented accumulation) ----------------
__global__ __launch_bounds__(256) void k_pool(const float* __restrict__ x,
                                              const float* __restrict__ scsh,
                                              const int* __restrict__ batch,
                                              float* __restrict__ pool,
                                              int* __restrict__ pcnt) {
  int c = threadIdx.x;
  const int RPB = (NN + 255) / 256;  // 79
  int r0 = blockIdx.x * RPB, r1 = min(r0 + RPB, NN);
  if (r0 >= r1) return;
  float sc = scsh[c], sh = scsh[HIDW + c];
  int curb = batch[r0];
  float acc = 0.f;
  int run = 0;
  for (int r = r0; r < r1; ++r) {
    int b = batch[r];
    if (b != curb) {
      atomicAdd(&pool[curb * HIDW + c], acc);
      if (c == 0) atomicAdd(&pcnt[curb], run);
      acc = 0.f; run = 0; curb = b;
    }
    float v = fmaxf(x[(size_t)r * HIDW + c] * sc + sh, 0.f);
    acc += v;
    run++;
  }
  atomicAdd(&pool[curb * HIDW + c], acc);
  if (c == 0) atomicAdd(&pcnt[curb], run);
}

// ---------------- whole head in one kernel (B=64 blocks) ----------------
__global__ __launch_bounds__(256) void k_head(const float* __restrict__ pool,
                                              const int* __restrict__ pcnt,
                                              const float* __restrict__ Wv, const float* __restrict__ bv,
                                              const float* __restrict__ Wo, const float* __restrict__ bo,
                                              const float* __restrict__ fusW, const float* __restrict__ fusB,
                                              const float* __restrict__ p1W, const float* __restrict__ p1b,
                                              const float* __restrict__ p2W, const float* __restrict__ p2b,
                                              float* __restrict__ out) {
  __shared__ float pr[HIDW], sA[HIDW], sB[HIDW], sH[128];
  int b = blockIdx.x, c = threadIdx.x;
  float invc = 1.f / fmaxf((float)pcnt[b], 1.f);
  pr[c] = pool[b * HIDW + c] * invc;
  __syncthreads();
  // hv = pool@Wv + bv
  float acc = bv[c];
  for (int k = 0; k < HIDW; ++k) acc += pr[k] * Wv[k * HIDW + c];
  sA[c] = acc;
  __syncthreads();
  // hx = hv@Wo + bo
  acc = bo[c];
  for (int k = 0; k < HIDW; ++k) acc += sA[k] * Wo[k * HIDW + c];
  sB[c] = acc;
  __syncthreads();
  // xf = relu([hx, pool]@fusW + fusB)
  acc = fusB[c];
  for (int k = 0; k < HIDW; ++k) acc += sB[k] * fusW[k * HIDW + c];
  for (int k = 0; k < HIDW; ++k) acc += pr[k] * fusW[(HIDW + k) * HIDW + c];
  float xf = fmaxf(acc, 0.f);
  __syncthreads();
  sA[c] = xf;
  __syncthreads();
  // h1 = relu(xf@p1W + p1b)
  if (c < 128) {
    acc = p1b[c];
    for (int k = 0; k < HIDW; ++k) acc += sA[k] * p1W[k * 128 + c];
    sH[c] = fmaxf(acc, 0.f);
  }
  __syncthreads();
  if (c == 0) {
    float s = p2b[0];
    for (int k = 0; k < 128; ++k) s += sH[k] * p2W[k];
    out[b] = s;
  }
}

// ---------------- launch ----------------
extern "C" void kernel_launch(void* const* d_in, const int* in_sizes, int n_in,
                              void* d_out, int out_size, void* d_ws, size_t ws_size,
                              hipStream_t stream) {
  // seq branch + Wq/bq/Wk/bk are dead code (softmax over singleton axis == 1).
  // gat_b cancels inside BatchNorm.
  const float* struct_x = (const float*)d_in[1];
  const int* edge = (const int*)d_in[3];
  const int* batch = (const int*)d_in[5];
  const float* projW = (const float*)d_in[12];
  const float* projB = (const float*)d_in[13];
  const float* gatW = (const float*)d_in[14];
  const float* attS = (const float*)d_in[15];
  const float* attD = (const float*)d_in[16];
  const float* bnG = (const float*)d_in[18];
  const float* bnB = (const float*)d_in[19];
  const float* Wv = (const float*)d_in[24];
  const float* bv = (const float*)d_in[25];
  const float* Wo = (const float*)d_in[26];
  const float* bo = (const float*)d_in[27];
  const float* fusW = (const float*)d_in[28];
  const float* fusB = (const float*)d_in[29];
  const float* p1W = (const float*)d_in[30];
  const float* p1b = (const float*)d_in[31];
  const float* p2W = (const float*)d_in[32];
  const float* p2b = (const float*)d_in[33];
  float* out = (float*)d_out;

  const int* e_src = edge;
  const int* e_dst = edge + NE;

  char* ws = (char*)d_ws;
  size_t off = 0;
  auto alloc = [&](size_t bytes) -> void* {
    void* p = ws + off;
    off = (off + bytes + 255) & ~(size_t)255;
    return p;
  };
  float* buf0 = (float*)alloc((size_t)NN * HIDW * 4);
  float* buf1 = (float*)alloc((size_t)NN * HIDW * 4);
  int* rowptr = (int*)alloc((NN + 1) * 4);
  int* srcs = (int*)alloc((size_t)NTOT * 4);
  float* asrc = (float*)alloc((size_t)NN * NHEADS * 4);
  float* adst = (float*)alloc((size_t)NN * NHEADS * 4);
  float* mr = (float*)alloc(512 * 4);
  // ---- zero-init region (single memset): cnt, cur, stats[4], pool, pcnt ----
  char* zero_base = ws + off;
  int* cnt = (int*)alloc(NN * 4);
  int* cur = (int*)alloc(NN * 4);
  float* stats = (float*)alloc(4 * 512 * 4);
  float* pool = (float*)alloc(NBATCH * HIDW * 4);
  int* pcnt = (int*)alloc(NBATCH * 4);
  size_t zero_bytes = (ws + off) - zero_base;

  const int TPB = 256;
  const int gEdge = (NTOT + TPB - 1) / TPB;

  hipMemsetAsync(zero_base, 0, zero_bytes, stream);

  // ---- CSR (self loops appended) ----
  k_hist<<<gEdge, TPB, 0, stream>>>(e_dst, cnt);
  k_scan<<<1, 1024, 0, stream>>>(cnt, rowptr);
  k_fill<<<gEdge, TPB, 0, stream>>>(e_src, e_dst, rowptr, cur, srcs);

  dim3 gemmGrid((NN + BM - 1) / BM, HIDW / BN);
  // struct projection: buf0 = relu(struct_x @ projW + projB)
  k_gemm<<<gemmGrid, 256, 0, stream>>>(struct_x, projW, projB, nullptr, nullptr, nullptr,
                                       buf0, nullptr, nullptr, NN, 128, HIDW, 0);

  for (int l = 0; l < NL; ++l) {
    // h = act(buf0) @ gat_W[l]; act = BN-affine+relu for l>0 (fused on A-load)
    k_gemm<<<gemmGrid, 256, 0, stream>>>(buf0, gatW + (size_t)l * HIDW * HIDW, nullptr,
                                         (l == 0) ? nullptr : mr,
                                         attS + l * HIDW, attD + l * HIDW,
                                         buf1, asrc, adst, NN, HIDW, HIDW, 1);
    k_agg<<<(NN * 64) / TPB, TPB, 0, stream>>>(buf1, rowptr, srcs, asrc, adst, buf0);
    k_bn_stats<<<256, 256, 0, stream>>>(buf0, stats + l * 512);
    k_bn_fin<<<1, 256, 0, stream>>>(stats + l * 512, bnG + l * HIDW, bnB + l * HIDW, mr);
  }

  // ---- mean pool (applies layer-3 BN affine + relu on the fly) ----
  k_pool<<<256, 256, 0, stream>>>(buf0, mr, batch, pool, pcnt);

  // ---- head ----
  k_head<<<NBATCH, 256, 0, stream>>>(pool, pcnt, Wv, bv, Wo, bo, fusW, fusB,
                                     p1W, p1b, p2W, p2b, out);
}

// Round 3
// 547.480 us; speedup vs baseline: 1.7613x; 1.3120x over previous
//
#include <hip/hip_runtime.h>
#include <math.h>

#define NN 20000
#define NE 320000
#define NTOT (NE + NN)
#define NBATCH 64
#define HIDW 256
#define NHEADS 8
#define HD 32
#define NL 4
#define BEPS 1e-5f
#define LSLOPE 0.2f

typedef __attribute__((ext_vector_type(8))) short s16x8;
typedef __attribute__((ext_vector_type(4))) float f32x4;

static __device__ __forceinline__ ushort f2bf(float f) {
  uint u = __float_as_uint(f);
  uint r = (u + 0x7fff + ((u >> 16) & 1)) >> 16;  // RNE
  return (ushort)r;
}
static __device__ __forceinline__ float bf2f(ushort h) {
  return __uint_as_float(((uint)h) << 16);
}

// ---------------- CSR build ----------------
__global__ void k_hist(const int* __restrict__ dst, int* __restrict__ cnt) {
  int i = blockIdx.x * blockDim.x + threadIdx.x;
  if (i >= NTOT) return;
  int d = (i < NE) ? dst[i] : (i - NE);
  atomicAdd(&cnt[d], 1);
}

__global__ __launch_bounds__(1024) void k_scan(const int* __restrict__ cnt,
                                               int* __restrict__ rowptr) {
  __shared__ int tsum[1024];
  int tid = threadIdx.x;
  const int per = (NN + 1023) / 1024;  // 20
  int start = tid * per;
  int local = 0;
  for (int j = 0; j < per; ++j) {
    int idx = start + j;
    if (idx < NN) local += cnt[idx];
  }
  tsum[tid] = local;
  __syncthreads();
  for (int off = 1; off < 1024; off <<= 1) {
    int v = (tid >= off) ? tsum[tid - off] : 0;
    __syncthreads();
    tsum[tid] += v;
    __syncthreads();
  }
  int run = (tid == 0) ? 0 : tsum[tid - 1];
  for (int j = 0; j < per; ++j) {
    int idx = start + j;
    if (idx < NN) { rowptr[idx] = run; run += cnt[idx]; }
  }
  if (tid == 1023) rowptr[NN] = tsum[1023];
}

__global__ void k_fill(const int* __restrict__ src, const int* __restrict__ dst,
                       const int* __restrict__ rowptr, int* __restrict__ cur,
                       int* __restrict__ srcs) {
  int i = blockIdx.x * blockDim.x + threadIdx.x;
  if (i >= NTOT) return;
  int s = (i < NE) ? src[i] : (i - NE);
  int d = (i < NE) ? dst[i] : (i - NE);
  int pos = rowptr[d] + atomicAdd(&cur[d], 1);
  srcs[pos] = s;
}

// ---------------- MFMA GEMM (split-bf16, fp32-equivalent accuracy) ----------------
// C[M,256] = act(A[M,K]) @ W[K,256]
// mode 0: Cf = relu(acc + bias)            (fp32 out)
// mode 1: Ch = bf16(acc) raw; asrc/adst = per-head dot with aS/aD (fp32)
// scsh != null: A elem (r,k) -> relu(v*scsh[k] + scsh[256+k]) on load
#define GBM 128
#define GBN 64
#define GBK 32
__global__ __launch_bounds__(256) void k_mfma(const float* __restrict__ A,
                                              const float* __restrict__ W,
                                              const float* __restrict__ bias,
                                              const float* __restrict__ scsh,
                                              const float* __restrict__ aS,
                                              const float* __restrict__ aD,
                                              float* __restrict__ Cf,
                                              ushort* __restrict__ Ch,
                                              float* __restrict__ asrc,
                                              float* __restrict__ adst,
                                              int M, int K, int mode) {
  __shared__ short As[2][GBM][40];  // [hi/lo][row][k], pad 32->40 (80B stride: 2-way banks)
  __shared__ short Ws[2][GBN][40];  // [hi/lo][col][k] (transposed W tile)
  int tid = threadIdx.x;
  int wid = tid >> 6, lane = tid & 63;
  int wr = wid >> 1, wc = wid & 1;
  int l15 = lane & 15, l4 = lane >> 4;
  int row0 = blockIdx.x * GBM, col0 = blockIdx.y * GBN;

  f32x4 acc[4][2] = {};

  // staging indices
  int sr = tid >> 1;             // A row 0..127
  int skh = (tid & 1) * 16;      // A k-sub: 0 or 16
  int wn = tid & 63;             // W col 0..63
  int wk0 = wid * 8;             // W k-sub base

  for (int k0 = 0; k0 < K; k0 += GBK) {
    // ---- stage A (fp32 -> hi/lo bf16) ----
    {
      int gr = row0 + sr;
      float va[16];
      if (gr < M) {
#pragma unroll
        for (int q = 0; q < 4; ++q) {
          float4 v = *reinterpret_cast<const float4*>(&A[(size_t)gr * K + k0 + skh + q * 4]);
          va[q * 4 + 0] = v.x; va[q * 4 + 1] = v.y; va[q * 4 + 2] = v.z; va[q * 4 + 3] = v.w;
        }
      } else {
#pragma unroll
        for (int j = 0; j < 16; ++j) va[j] = 0.f;
      }
      if (scsh) {
#pragma unroll
        for (int j = 0; j < 16; ++j) {
          int kc = k0 + skh + j;
          va[j] = fmaxf(va[j] * scsh[kc] + scsh[HIDW + kc], 0.f);
        }
      }
      s16x8 h0, h1, L0, L1;
#pragma unroll
      for (int j = 0; j < 8; ++j) {
        ushort h = f2bf(va[j]);
        h0[j] = (short)h;
        L0[j] = (short)f2bf(va[j] - bf2f(h));
      }
#pragma unroll
      for (int j = 0; j < 8; ++j) {
        ushort h = f2bf(va[8 + j]);
        h1[j] = (short)h;
        L1[j] = (short)f2bf(va[8 + j] - bf2f(h));
      }
      *reinterpret_cast<s16x8*>(&As[0][sr][skh]) = h0;
      *reinterpret_cast<s16x8*>(&As[0][sr][skh + 8]) = h1;
      *reinterpret_cast<s16x8*>(&As[1][sr][skh]) = L0;
      *reinterpret_cast<s16x8*>(&As[1][sr][skh + 8]) = L1;
    }
    // ---- stage W (transposed, hi/lo) ----
    {
      s16x8 wh, wl;
#pragma unroll
      for (int j = 0; j < 8; ++j) {
        float wv = W[(size_t)(k0 + wk0 + j) * HIDW + col0 + wn];
        ushort h = f2bf(wv);
        wh[j] = (short)h;
        wl[j] = (short)f2bf(wv - bf2f(h));
      }
      *reinterpret_cast<s16x8*>(&Ws[0][wn][wk0]) = wh;
      *reinterpret_cast<s16x8*>(&Ws[1][wn][wk0]) = wl;
    }
    __syncthreads();

    // ---- fragments + MFMA ----
    s16x8 af[4][2], bfv[2][2];
    int ak = l4 * 8;
#pragma unroll
    for (int mf = 0; mf < 4; ++mf) {
      int ar = wr * 64 + mf * 16 + l15;
      af[mf][0] = *reinterpret_cast<const s16x8*>(&As[0][ar][ak]);
      af[mf][1] = *reinterpret_cast<const s16x8*>(&As[1][ar][ak]);
    }
#pragma unroll
    for (int nf = 0; nf < 2; ++nf) {
      int bn = wc * 32 + nf * 16 + l15;
      bfv[nf][0] = *reinterpret_cast<const s16x8*>(&Ws[0][bn][ak]);
      bfv[nf][1] = *reinterpret_cast<const s16x8*>(&Ws[1][bn][ak]);
    }
#pragma unroll
    for (int mf = 0; mf < 4; ++mf)
#pragma unroll
      for (int nf = 0; nf < 2; ++nf) {
        acc[mf][nf] = __builtin_amdgcn_mfma_f32_16x16x32_bf16(af[mf][0], bfv[nf][0], acc[mf][nf], 0, 0, 0);
        acc[mf][nf] = __builtin_amdgcn_mfma_f32_16x16x32_bf16(af[mf][0], bfv[nf][1], acc[mf][nf], 0, 0, 0);
        acc[mf][nf] = __builtin_amdgcn_mfma_f32_16x16x32_bf16(af[mf][1], bfv[nf][0], acc[mf][nf], 0, 0, 0);
      }
    __syncthreads();
  }

  // C/D layout (m89-verified): col = lane&15, row = (lane>>4)*4 + reg
  if (mode == 0) {
#pragma unroll
    for (int mf = 0; mf < 4; ++mf)
#pragma unroll
      for (int reg = 0; reg < 4; ++reg) {
        int r = row0 + wr * 64 + mf * 16 + l4 * 4 + reg;
        if (r >= M) continue;
#pragma unroll
        for (int nf = 0; nf < 2; ++nf) {
          int c = col0 + wc * 32 + nf * 16 + l15;
          Cf[(size_t)r * HIDW + c] = fmaxf(acc[mf][nf][reg] + bias[c], 0.f);
        }
      }
  } else {
    int hg = blockIdx.y * 2 + wc;  // this wave's 32 cols == head hg exactly
    float aSv[2], aDv[2];
#pragma unroll
    for (int nf = 0; nf < 2; ++nf) {
      aSv[nf] = aS[hg * HD + nf * 16 + l15];
      aDv[nf] = aD[hg * HD + nf * 16 + l15];
    }
#pragma unroll
    for (int mf = 0; mf < 4; ++mf)
#pragma unroll
      for (int reg = 0; reg < 4; ++reg) {
        int r = row0 + wr * 64 + mf * 16 + l4 * 4 + reg;
        bool ok = (r < M);
        float pa = 0.f, pd = 0.f;
#pragma unroll
        for (int nf = 0; nf < 2; ++nf) {
          float v = acc[mf][nf][reg];
          if (ok) {
            int c = col0 + wc * 32 + nf * 16 + l15;
            Ch[(size_t)r * HIDW + c] = f2bf(v);
          }
          pa += v * aSv[nf];
          pd += v * aDv[nf];
        }
        pa += __shfl_xor(pa, 1); pa += __shfl_xor(pa, 2);
        pa += __shfl_xor(pa, 4); pa += __shfl_xor(pa, 8);
        pd += __shfl_xor(pd, 1); pd += __shfl_xor(pd, 2);
        pd += __shfl_xor(pd, 4); pd += __shfl_xor(pd, 8);
        if (ok && l15 == 0) {
          asrc[r * NHEADS + hg] = pa;
          adst[r * NHEADS + hg] = pd;
        }
      }
  }
}

// ---------------- fused GAT aggregation: softmax + bf16 gather in one pass ----------------
__global__ __launch_bounds__(256) void k_agg(const ushort* __restrict__ h,
                                             const int* __restrict__ rowptr,
                                             const int* __restrict__ srcs,
                                             const float* __restrict__ asrc,
                                             const float* __restrict__ adst,
                                             float* __restrict__ out) {
  int wid = (blockIdx.x * blockDim.x + threadIdx.x) >> 6;
  int lane = threadIdx.x & 63;
  if (wid >= NN) return;
  int hh = lane >> 3;
  float adn = adst[wid * NHEADS + hh];
  int beg = rowptr[wid], end = rowptr[wid + 1];
  float4 acc = make_float4(0.f, 0.f, 0.f, 0.f);
  float ssum = 0.f;
  for (int p = beg; p < end; ++p) {
    int s = srcs[p];
    float e = asrc[s * NHEADS + hh] + adn;
    e = (e >= 0.f) ? e : LSLOPE * e;
    float ex = __expf(e);  // max-subtraction removable: logits are O(1)
    ssum += ex;
    ushort4 v = *reinterpret_cast<const ushort4*>(&h[(size_t)s * HIDW + lane * 4]);
    acc.x += ex * bf2f(v.x);
    acc.y += ex * bf2f(v.y);
    acc.z += ex * bf2f(v.z);
    acc.w += ex * bf2f(v.w);
  }
  float inv = 1.f / ssum;
  acc.x *= inv; acc.y *= inv; acc.z *= inv; acc.w *= inv;
  *reinterpret_cast<float4*>(&out[(size_t)wid * HIDW + lane * 4]) = acc;
}

// ---------------- BatchNorm stats -> (scale, shift) ----------------
__global__ void k_bn_stats(const float* __restrict__ x, float* __restrict__ stats) {
  int c = threadIdx.x;
  float s = 0.f, s2 = 0.f;
  for (int r = blockIdx.x; r < NN; r += gridDim.x) {
    float v = x[(size_t)r * HIDW + c];
    s += v;
    s2 += v * v;
  }
  atomicAdd(&stats[c], s);
  atomicAdd(&stats[HIDW + c], s2);
}

__global__ void k_bn_fin(const float* __restrict__ stats, const float* __restrict__ g,
                         const float* __restrict__ b, float* __restrict__ scsh) {
  int c = threadIdx.x;
  float mean = stats[c] * (1.f / NN);
  float var = stats[HIDW + c] * (1.f / NN) - mean * mean;
  var = fmaxf(var, 0.f);
  float sc = g[c] * rsqrtf(var + BEPS);
  scsh[c] = sc;
  scsh[HIDW + c] = b[c] - mean * sc;
}

// ---------------- mean pool (sorted batch, segmented accumulation) ----------------
__global__ __launch_bounds__(256) void k_pool(const float* __restrict__ x,
                                              const float* __restrict__ scsh,
                                              const int* __restrict__ batch,
                                              float* __restrict__ pool,
                                              int* __restrict__ pcnt) {
  int c = threadIdx.x;
  const int RPB = (NN + 255) / 256;  // 79
  int r0 = blockIdx.x * RPB, r1 = min(r0 + RPB, NN);
  if (r0 >= r1) return;
  float sc = scsh[c], sh = scsh[HIDW + c];
  int curb = batch[r0];
  float acc = 0.f;
  int run = 0;
  for (int r = r0; r < r1; ++r) {
    int b = batch[r];
    if (b != curb) {
      atomicAdd(&pool[curb * HIDW + c], acc);
      if (c == 0) atomicAdd(&pcnt[curb], run);
      acc = 0.f; run = 0; curb = b;
    }
    float v = fmaxf(x[(size_t)r * HIDW + c] * sc + sh, 0.f);
    acc += v;
    run++;
  }
  atomicAdd(&pool[curb * HIDW + c], acc);
  if (c == 0) atomicAdd(&pcnt[curb], run);
}

// ---------------- whole head in one kernel (B=64 blocks) ----------------
__global__ __launch_bounds__(256) void k_head(const float* __restrict__ pool,
                                              const int* __restrict__ pcnt,
                                              const float* __restrict__ Wv, const float* __restrict__ bv,
                                              const float* __restrict__ Wo, const float* __restrict__ bo,
                                              const float* __restrict__ fusW, const float* __restrict__ fusB,
                                              const float* __restrict__ p1W, const float* __restrict__ p1b,
                                              const float* __restrict__ p2W, const float* __restrict__ p2b,
                                              float* __restrict__ out) {
  __shared__ float pr[HIDW], sA[HIDW], sB[HIDW], sH[128];
  int b = blockIdx.x, c = threadIdx.x;
  float invc = 1.f / fmaxf((float)pcnt[b], 1.f);
  pr[c] = pool[b * HIDW + c] * invc;
  __syncthreads();
  float acc = bv[c];
  for (int k = 0; k < HIDW; ++k) acc += pr[k] * Wv[k * HIDW + c];
  sA[c] = acc;
  __syncthreads();
  acc = bo[c];
  for (int k = 0; k < HIDW; ++k) acc += sA[k] * Wo[k * HIDW + c];
  sB[c] = acc;
  __syncthreads();
  acc = fusB[c];
  for (int k = 0; k < HIDW; ++k) acc += sB[k] * fusW[k * HIDW + c];
  for (int k = 0; k < HIDW; ++k) acc += pr[k] * fusW[(HIDW + k) * HIDW + c];
  float xf = fmaxf(acc, 0.f);
  __syncthreads();
  sA[c] = xf;
  __syncthreads();
  if (c < 128) {
    acc = p1b[c];
    for (int k = 0; k < HIDW; ++k) acc += sA[k] * p1W[k * 128 + c];
    sH[c] = fmaxf(acc, 0.f);
  }
  __syncthreads();
  if (c == 0) {
    float s = p2b[0];
    for (int k = 0; k < 128; ++k) s += sH[k] * p2W[k];
    out[b] = s;
  }
}

// ---------------- launch ----------------
extern "C" void kernel_launch(void* const* d_in, const int* in_sizes, int n_in,
                              void* d_out, int out_size, void* d_ws, size_t ws_size,
                              hipStream_t stream) {
  // seq branch + Wq/bq/Wk/bk are dead code (softmax over singleton axis == 1).
  // gat_b cancels inside BatchNorm.
  const float* struct_x = (const float*)d_in[1];
  const int* edge = (const int*)d_in[3];
  const int* batch = (const int*)d_in[5];
  const float* projW = (const float*)d_in[12];
  const float* projB = (const float*)d_in[13];
  const float* gatW = (const float*)d_in[14];
  const float* attS = (const float*)d_in[15];
  const float* attD = (const float*)d_in[16];
  const float* bnG = (const float*)d_in[18];
  const float* bnB = (const float*)d_in[19];
  const float* Wv = (const float*)d_in[24];
  const float* bv = (const float*)d_in[25];
  const float* Wo = (const float*)d_in[26];
  const float* bo = (const float*)d_in[27];
  const float* fusW = (const float*)d_in[28];
  const float* fusB = (const float*)d_in[29];
  const float* p1W = (const float*)d_in[30];
  const float* p1b = (const float*)d_in[31];
  const float* p2W = (const float*)d_in[32];
  const float* p2b = (const float*)d_in[33];
  float* out = (float*)d_out;

  const int* e_src = edge;
  const int* e_dst = edge + NE;

  char* ws = (char*)d_ws;
  size_t off = 0;
  auto alloc = [&](size_t bytes) -> void* {
    void* p = ws + off;
    off = (off + bytes + 255) & ~(size_t)255;
    return p;
  };
  float* buf0 = (float*)alloc((size_t)NN * HIDW * 4);   // fp32 activations
  ushort* hb = (ushort*)alloc((size_t)NN * HIDW * 2);   // bf16 h for gather
  int* rowptr = (int*)alloc((NN + 1) * 4);
  int* srcs = (int*)alloc((size_t)NTOT * 4);
  float* asrc = (float*)alloc((size_t)NN * NHEADS * 4);
  float* adst = (float*)alloc((size_t)NN * NHEADS * 4);
  float* mr = (float*)alloc(512 * 4);
  // ---- zero-init region (single memset) ----
  char* zero_base = ws + off;
  int* cnt = (int*)alloc(NN * 4);
  int* cur = (int*)alloc(NN * 4);
  float* stats = (float*)alloc(4 * 512 * 4);
  float* pool = (float*)alloc(NBATCH * HIDW * 4);
  int* pcnt = (int*)alloc(NBATCH * 4);
  size_t zero_bytes = (ws + off) - zero_base;

  const int TPB = 256;
  const int gEdge = (NTOT + TPB - 1) / TPB;

  hipMemsetAsync(zero_base, 0, zero_bytes, stream);

  // ---- CSR (self loops appended) ----
  k_hist<<<gEdge, TPB, 0, stream>>>(e_dst, cnt);
  k_scan<<<1, 1024, 0, stream>>>(cnt, rowptr);
  k_fill<<<gEdge, TPB, 0, stream>>>(e_src, e_dst, rowptr, cur, srcs);

  dim3 gemmGrid((NN + GBM - 1) / GBM, HIDW / GBN);  // 157 x 4
  // struct projection: buf0 = relu(struct_x @ projW + projB)
  k_mfma<<<gemmGrid, 256, 0, stream>>>(struct_x, projW, projB, nullptr, nullptr, nullptr,
                                       buf0, nullptr, nullptr, nullptr, NN, 128, 0);

  for (int l = 0; l < NL; ++l) {
    // h = act(buf0) @ gat_W[l]; act = BN-affine+relu for l>0 (fused on A-load)
    k_mfma<<<gemmGrid, 256, 0, stream>>>(buf0, gatW + (size_t)l * HIDW * HIDW, nullptr,
                                         (l == 0) ? nullptr : mr,
                                         attS + l * HIDW, attD + l * HIDW,
                                         nullptr, hb, asrc, adst, NN, HIDW, 1);
    k_agg<<<(NN * 64) / TPB, TPB, 0, stream>>>(hb, rowptr, srcs, asrc, adst, buf0);
    k_bn_stats<<<256, 256, 0, stream>>>(buf0, stats + l * 512);
    k_bn_fin<<<1, 256, 0, stream>>>(stats + l * 512, bnG + l * HIDW, bnB + l * HIDW, mr);
  }

  // ---- mean pool (applies layer-3 BN affine + relu on the fly) ----
  k_pool<<<256, 256, 0, stream>>>(buf0, mr, batch, pool, pcnt);

  // ---- head ----
  k_head<<<NBATCH, 256, 0, stream>>>(pool, pcnt, Wv, bv, Wo, bo, fusW, fusB,
                                     p1W, p1b, p2W, p2b, out);
}